// Round 11
// baseline (427.626 us; speedup 1.0000x reference)
//
#include <hip/hip_runtime.h>

// ---------------------------------------------------------------------------
// TransformerBlock on MI355X (gfx950) — round 15.
// Token-major: t = s*B + b, x is (8192, 1024).
// NEW: gemm256p — faithful 4-phase 256x256 BK=64 pipeline (T3+T4) for MLP1
// only (grid 256 = exactly 1 block/CU). Per phase: ds-read quadrant frags ||
// stage 1 half-tile (tile u+1) -> barrier -> setprio+16 MFMA -> barrier.
// vmcnt(2) ONLY at phase 0 (counted; never a mid-loop drain). LDS 128KB
// 2-buffer; XOR swizzle g(a)=a^(((a>>7)&3)<<5) applied to global SOURCE at
// stage (linear LDS dest) and to read addr -> 4-way (not 16-way) conflicts.
// Other GEMMs stay gemm_bt2 (128^2 plateau ~710 TF; grids don't fit 256^2).
// Attention v9 (64-key chunks) unchanged from r14.
// ws slots (MiB): S0[0,16) h/vt/m; S1[16,32) q/ctx; S2[32,48) k/g.lo;
// S3[48,64) vtmp/l/g.hi; [64,80) bf16 weights. d_out = attn partial scratch.
// ---------------------------------------------------------------------------

typedef __bf16 bf16;
typedef bf16 bf16x8 __attribute__((ext_vector_type(8)));
typedef bf16 bf16x4 __attribute__((ext_vector_type(4)));
typedef float f32x4 __attribute__((ext_vector_type(4)));

#define MFMA16x16x32(A, B, C) __builtin_amdgcn_mfma_f32_16x16x32_bf16(A, B, C, 0, 0, 0)

__device__ __forceinline__ void gload16(const void* g, void* l) {
  __builtin_amdgcn_global_load_lds(
      (const __attribute__((address_space(1))) void*)g,
      (__attribute__((address_space(3))) void*)l, 16, 0, 0);
}

// ---------------- f32 -> bf16 weight conversion (all 4 weights) ------------
__global__ __launch_bounds__(256) void wcvt4(
    const float* __restrict__ s0, bf16* __restrict__ d0,
    const float* __restrict__ s1, bf16* __restrict__ d1,
    const float* __restrict__ s2, bf16* __restrict__ d2,
    const float* __restrict__ s3, bf16* __restrict__ d3)
{
  const int gid = blockIdx.x * 256 + threadIdx.x;  // quad index, 2097152 total
  const float* s; bf16* d; int off;
  if (gid < 786432)       { s = s0; d = d0; off = gid; }
  else if (gid < 1048576) { s = s1; d = d1; off = gid - 786432; }
  else if (gid < 1572864) { s = s2; d = d2; off = gid - 1048576; }
  else                    { s = s3; d = d3; off = gid - 1572864; }
  const int i = off * 4;
  const float4 v = *(const float4*)(s + i);
  bf16x4 o;
  o[0] = (bf16)v.x; o[1] = (bf16)v.y; o[2] = (bf16)v.z; o[3] = (bf16)v.w;
  *(bf16x4*)(d + i) = o;
}

// ---------------- RMSNorm: (8192 x 1024) f32 -> bf16 -----------------------
__global__ __launch_bounds__(256) void rmsnorm_kernel(
    const float* __restrict__ x, const float* __restrict__ w, bf16* __restrict__ out)
{
  const int row = blockIdx.x;
  const int tid = threadIdx.x;
  const float4 v = *(const float4*)(x + (size_t)row * 1024 + tid * 4);
  float ss = v.x * v.x + v.y * v.y + v.z * v.z + v.w * v.w;
#pragma unroll
  for (int off = 1; off < 64; off <<= 1) ss += __shfl_xor(ss, off, 64);
  __shared__ float red[4];
  if ((tid & 63) == 0) red[tid >> 6] = ss;
  __syncthreads();
  const float tot = red[0] + red[1] + red[2] + red[3];
  const float inv = rsqrtf(tot * (1.0f / 1024.0f) + 1e-8f);
  const float4 g = *(const float4*)(w + tid * 4);
  bf16x4 o;
  o[0] = (bf16)(v.x * g.x * inv);
  o[1] = (bf16)(v.y * g.y * inv);
  o[2] = (bf16)(v.z * g.z * inv);
  o[3] = (bf16)(v.w * g.w * inv);
  *(bf16x4*)(out + (size_t)row * 1024 + tid * 4) = o;
}

// ---------------- GEMM: C = A * W^T + bias, 128x128, 2-phase ---------------
enum { EPI_BF16 = 0, EPI_RES = 1, EPI_GELU = 2, EPI_QKV = 3 };

template <int EPI>
__global__ __launch_bounds__(256, 4) void gemm_bt2(
    const bf16* __restrict__ A,   // M x K
    const bf16* __restrict__ B,   // N x K
    const float* __restrict__ bias,
    const float* res,             // may alias outF
    float* outF, bf16* outQ, bf16* outK, bf16* outV,
    int M, int N, int K)
{
  __shared__ bf16 lds[2][8192];  // 2 buffers x (As 4096 + Bs 4096) = 32 KB
  const int tid = threadIdx.x;
  const int Nb = N >> 7;
  const int lin = blockIdx.x;
  const int sup = lin / (Nb << 4);
  const int rem = lin - sup * (Nb << 4);
  const int bm = (sup << 4) + (rem & 15);
  const int bn = rem >> 4;
  const int w = tid >> 6, lane = tid & 63;
  const int q = lane >> 4, lr = lane & 15;
  const int wr = (w >> 1) * 64, wc = (w & 1) * 64;
  f32x4 acc[4][4] = {};
  const int srow = lane >> 2;
  const int gch = ((lane & 3) - ((lane >> 3) & 3)) & 3;
  const bf16* Ab = A + (size_t)(bm * 128) * K;
  const bf16* Bb = B + (size_t)(bn * 128) * K;
  const int sw = ((q + (lr >> 1)) & 3) * 16;
  const int NK = K >> 5;

#define STAGE(dst, k0)                                                        \
  {                                                                           \
    bf16* De = (dst);                                                         \
    _Pragma("unroll")                                                         \
    for (int c = 0; c < 2; c++) {                                             \
      const int r = (w * 2 + c) * 16 + srow;                                  \
      gload16(Ab + (size_t)r * K + (k0) + gch * 8, De + (w * 2 + c) * 512);   \
      gload16(Bb + (size_t)r * K + (k0) + gch * 8, De + 4096 + (w * 2 + c) * 512); \
    }                                                                         \
  }

  STAGE(&lds[0][0], 0);
  __syncthreads();  // tile 0 visible
#pragma unroll 1
  for (int u = 0; u < NK; ++u) {
    bf16* cur = &lds[u & 1][0];
    bf16* nxt = &lds[(u + 1) & 1][0];
    if (u + 1 < NK) STAGE(nxt, (u + 1) * 32);
    const char* As = (const char*)cur;
    const char* Bs = (const char*)(cur + 4096);
    bf16x8 af[4], bfr[4];
#pragma unroll
    for (int mt = 0; mt < 4; mt++)
      af[mt] = *(const bf16x8*)(As + (wr + mt * 16 + lr) * 64 + sw);
#pragma unroll
    for (int nt = 0; nt < 4; nt++)
      bfr[nt] = *(const bf16x8*)(Bs + (wc + nt * 16 + lr) * 64 + sw);
#pragma unroll
    for (int mt = 0; mt < 4; mt++)
#pragma unroll
      for (int nt = 0; nt < 4; nt++)
        acc[mt][nt] = MFMA16x16x32(af[mt], bfr[nt], acc[mt][nt]);
    __syncthreads();
  }
#undef STAGE

  const int gm0 = bm * 128 + wr + q * 4;
  const int gn0 = bn * 128 + wc + lr;
  bf16* outs = nullptr;
  if constexpr (EPI == EPI_QKV) {
    const int reg = (bn * 128) >> 10;
    outs = reg == 0 ? outQ : (reg == 1 ? outK : outV);
  } else {
    outs = outQ;
  }
#pragma unroll
  for (int nt = 0; nt < 4; nt++) {
    const int gn = gn0 + nt * 16;
    const float bv = bias[gn];
#pragma unroll
    for (int mt = 0; mt < 4; mt++) {
#pragma unroll
      for (int r = 0; r < 4; r++) {
        float v = acc[mt][nt][r] + bv;
        const int gm = gm0 + mt * 16 + r;
        if constexpr (EPI == EPI_GELU) {
          v = 0.5f * v * (1.0f + erff(v * 0.70710678118654752f));
          outs[(size_t)gm * N + gn] = (bf16)v;
        } else if constexpr (EPI == EPI_BF16) {
          outs[(size_t)gm * N + gn] = (bf16)v;
        } else if constexpr (EPI == EPI_QKV) {
          outs[(size_t)gm * 1024 + (gn & 1023)] = (bf16)v;
        } else {
          const size_t idx = (size_t)gm * N + gn;
          outF[idx] = v + res[idx];
        }
      }
    }
  }
}

// ---------------- GEMM 256x256 4-phase pipelined (MLP1/GELU) ---------------
// 512 thr = 8 waves (2M x 4N); per-wave C = 128x64 (acc[8][4]).
// BK=64; LDS 2 x 64KB: [A0 16K][A1 16K][B0 16K][B1 16K] per buffer.
// Swizzle g(a)=a^(((a>>7)&3)<<5): LDS[g(a)]=logical[a]; stage fetches
// global at g(dest) (linear LDS dest per gload_lds rule); reads use g(a').
// Per iter u (tile=BK=64): 4 phases; phase p stages half-tile p of tile u+1
// and computes C-quadrant p. vmcnt(2) only at phase 0. 2 barriers/phase:
// trailing barrier guarantees all reads of cur done (compiler lgkm waits
// precede MFMA) before next iter stages over the other buffer.
__global__ __launch_bounds__(512, 2) void gemm256p(
    const bf16* __restrict__ A,   // M x K
    const bf16* __restrict__ B,   // N x K
    const float* __restrict__ bias,
    bf16* __restrict__ outO,
    int M, int N, int K)
{
  __shared__ __align__(16) char ldsb[131072];
  const int tid = threadIdx.x;
  const int w = tid >> 6, lane = tid & 63;
  const int q = lane >> 4, lr = lane & 15;
  const int wm = w >> 2, wn = w & 3;
  const int nbn = N >> 8;
  const int cpx = gridDim.x >> 3;
  const int lin = blockIdx.x;
  const int wg = (lin & 7) * cpx + (lin >> 3);
  const int bm = wg / nbn, bn = wg - bm * nbn;
  const bf16* Ab = A + (size_t)(bm * 256) * K;
  const bf16* Bb = B + (size_t)(bn * 256) * K;
  f32x4 acc[8][4] = {};
  const int NK = K >> 6;

  // staging geometry: thread t writes linear dest bytes {t*16, 8192+t*16}
  // per half-tile; fetches global logical position g(dest).
  const int rA = tid >> 3;                                   // 0..63
  const int stgc = (((tid & 7) * 16) ^ (((tid >> 3) & 3) << 5)) >> 1;  // elems
  // reader XOR: inner_ks = (ks*64 + q*16) ^ ((lr&3)<<5)
  const int x5 = (lr & 3) << 5;
  const int in0 = (q * 16) ^ x5;
  const int in1 = (64 + q * 16) ^ x5;
  const char* bmyc0;  // set per-iter

  // one half-tile stage: 2 gload16/thread. sect: A0=0 A1=16384 B0=32768 B1=49152
#define STG(bufoff, sect, srcp)                                               \
  {                                                                           \
    gload16((srcp) + (size_t)rA * K, ldsb + (bufoff) + (sect) + tid * 16);    \
    gload16((srcp) + (size_t)(rA + 64) * K,                                   \
            ldsb + (bufoff) + (sect) + 8192 + tid * 16);                      \
  }

  // prologue: tile 0 fully into buffer 0
  STG(0, 0,     Ab + stgc);
  STG(0, 16384, Ab + (size_t)128 * K + stgc);
  STG(0, 32768, Bb + stgc);
  STG(0, 49152, Bb + (size_t)128 * K + stgc);

  bf16x8 af[4][2], bfv[4][2];
#pragma unroll 1
  for (int u = 0; u < NK; ++u) {
    const int cu = (u & 1) << 16;       // 0 / 65536
    const int nb = ((u + 1) & 1) << 16;
    const int kn = (u + 1) << 6;
    const bool st = (u + 1 < NK);
    const char* amy = ldsb + cu + wm * 16384;
    const char* bmy = ldsb + cu + 32768 + (wn >> 1) * 16384;
    const int brow = (wn & 1) * 64;
    // ================= phase 0: quadrant (mtH0, ntH0) =================
    if (st) { STG(nb, 0, Ab + kn + stgc); }           // A-half0 of u+1
    if (st) asm volatile("s_waitcnt vmcnt(2)");       // tile u's 8 landed
    else    asm volatile("s_waitcnt vmcnt(0)");
    asm volatile("s_barrier" ::: "memory");           // full: no read hoisting
#pragma unroll
    for (int m2 = 0; m2 < 4; m2++) {
      af[m2][0] = *(const bf16x8*)(amy + (m2 * 16 + lr) * 128 + in0);
      af[m2][1] = *(const bf16x8*)(amy + (m2 * 16 + lr) * 128 + in1);
    }
#pragma unroll
    for (int n2 = 0; n2 < 2; n2++) {
      bfv[n2][0] = *(const bf16x8*)(bmy + (brow + n2 * 16 + lr) * 128 + in0);
      bfv[n2][1] = *(const bf16x8*)(bmy + (brow + n2 * 16 + lr) * 128 + in1);
    }
    __builtin_amdgcn_s_setprio(1);
#pragma unroll
    for (int m2 = 0; m2 < 4; m2++)
#pragma unroll
      for (int n2 = 0; n2 < 2; n2++) {
        acc[m2][n2] = MFMA16x16x32(af[m2][0], bfv[n2][0], acc[m2][n2]);
        acc[m2][n2] = MFMA16x16x32(af[m2][1], bfv[n2][1], acc[m2][n2]);
      }
    __builtin_amdgcn_s_setprio(0);
    __builtin_amdgcn_s_barrier();
    // ================= phase 1: quadrant (mtH0, ntH1) =================
#pragma unroll
    for (int n2 = 2; n2 < 4; n2++) {
      bfv[n2][0] = *(const bf16x8*)(bmy + (brow + n2 * 16 + lr) * 128 + in0);
      bfv[n2][1] = *(const bf16x8*)(bmy + (brow + n2 * 16 + lr) * 128 + in1);
    }
    if (st) { STG(nb, 16384, Ab + (size_t)128 * K + kn + stgc); }  // A-half1
    __builtin_amdgcn_s_barrier();
    __builtin_amdgcn_s_setprio(1);
#pragma unroll
    for (int m2 = 0; m2 < 4; m2++)
#pragma unroll
      for (int n2 = 2; n2 < 4; n2++) {
        acc[m2][n2] = MFMA16x16x32(af[m2][0], bfv[n2][0], acc[m2][n2]);
        acc[m2][n2] = MFMA16x16x32(af[m2][1], bfv[n2][1], acc[m2][n2]);
      }
    __builtin_amdgcn_s_setprio(0);
    __builtin_amdgcn_s_barrier();
    // ================= phase 2: quadrant (mtH1, ntH0) =================
#pragma unroll
    for (int m2 = 0; m2 < 4; m2++) {
      af[m2][0] = *(const bf16x8*)(amy + ((m2 + 4) * 16 + lr) * 128 + in0);
      af[m2][1] = *(const bf16x8*)(amy + ((m2 + 4) * 16 + lr) * 128 + in1);
    }
    if (st) { STG(nb, 32768, Bb + kn + stgc); }       // B-half0
    __builtin_amdgcn_s_barrier();
    __builtin_amdgcn_s_setprio(1);
#pragma unroll
    for (int m2 = 0; m2 < 4; m2++)
#pragma unroll
      for (int n2 = 0; n2 < 2; n2++) {
        acc[m2 + 4][n2] = MFMA16x16x32(af[m2][0], bfv[n2][0], acc[m2 + 4][n2]);
        acc[m2 + 4][n2] = MFMA16x16x32(af[m2][1], bfv[n2][1], acc[m2 + 4][n2]);
      }
    __builtin_amdgcn_s_setprio(0);
    __builtin_amdgcn_s_barrier();
    // ================= phase 3: quadrant (mtH1, ntH1) =================
    if (st) { STG(nb, 49152, Bb + (size_t)128 * K + kn + stgc); }  // B-half1
    __builtin_amdgcn_s_barrier();
    __builtin_amdgcn_s_setprio(1);
#pragma unroll
    for (int m2 = 0; m2 < 4; m2++)
#pragma unroll
      for (int n2 = 2; n2 < 4; n2++) {
        acc[m2 + 4][n2] = MFMA16x16x32(af[m2][0], bfv[n2][0], acc[m2 + 4][n2]);
        acc[m2 + 4][n2] = MFMA16x16x32(af[m2][1], bfv[n2][1], acc[m2 + 4][n2]);
      }
    __builtin_amdgcn_s_setprio(0);
    __builtin_amdgcn_s_barrier();
  }
#undef STG
  (void)bmyc0;

  // ---- epilogue: GELU + bf16 store (indexing verified in r8) ----
  const int gm0 = bm * 256 + wm * 128 + q * 4;
  const int gn0 = bn * 256 + wn * 64 + lr;
#pragma unroll
  for (int nt = 0; nt < 4; nt++) {
    const int gn = gn0 + nt * 16;
    const float bv = bias[gn];
#pragma unroll
    for (int mt = 0; mt < 8; mt++) {
#pragma unroll
      for (int r = 0; r < 4; r++) {
        float v = acc[mt][nt][r] + bv;
        v = 0.5f * v * (1.0f + erff(v * 0.70710678118654752f));
        outO[(size_t)(gm0 + mt * 16 + r) * N + gn] = (bf16)v;
      }
    }
  }
}

// ---------------- V transpose: vtmp (t,n) -> vt[bh][dim][key] --------------
__global__ __launch_bounds__(256) void vtrans_kernel(
    const bf16* __restrict__ vtmp, bf16* __restrict__ vt)
{
  __shared__ bf16 tile[64 * 72];
  const int kt = blockIdx.x;
  const int dt = blockIdx.y;
  const int bh = blockIdx.z;
  const int b = bh >> 1, h = bh & 1;
  const int tid = threadIdx.x;
#pragma unroll
  for (int it = 0; it < 2; it++) {
    const int key = it * 32 + (tid >> 3);
    const int dc = (tid & 7) * 8;
    const bf16x8 v = *(const bf16x8*)(vtmp +
        (size_t)((kt * 64 + key) * 4 + b) * 1024 + h * 512 + dt * 64 + dc);
    *(bf16x8*)&tile[key * 72 + dc] = v;
  }
  __syncthreads();
#pragma unroll
  for (int it = 0; it < 2; it++) {
    const int dim = it * 32 + (tid >> 3);
    const int kc = (tid & 7) * 8;
    bf16x8 o;
#pragma unroll
    for (int j = 0; j < 8; j++) o[j] = tile[(kc + j) * 72 + dim];
    *(bf16x8*)(vt + (size_t)bh * (1u << 20) +
               (size_t)(dt * 64 + dim) * 2048 + kt * 64 + kc) = o;
  }
}

// ---------------- Attention v9: 12 waves, 64-key chunks --------------------
__global__ __launch_bounds__(768, 3) void attn_kernel(
    const bf16* __restrict__ qb, const bf16* __restrict__ kb,
    const bf16* __restrict__ vtg, bf16* __restrict__ opart,
    float* __restrict__ lpart)
{
  __shared__ bf16 Ks[2][64 * 520];   // 2 x 66560 B
  __shared__ bf16 Ps[2][4][16 * 72]; // 2 x  9216 B  (151552 total)
  const int bh = blockIdx.x;          // 0..7 -> XCD affinity
  const int y = blockIdx.y;           // 0..31
  const int b = bh >> 1, h = bh & 1;
  const int tid = threadIdx.x;
  const int w = tid >> 6, lane = tid & 63;
  const int q = lane >> 4, lr = lane & 15;
  const float sc = 0.044194173824159216f;  // 1/sqrt(512)

  if (w < 4) {
    // ================= S-waves =================
    const bf16* krow0 = kb + (size_t)b * 1024 + h * 512 + lane * 8;  // per-lane 16B
    for (int piece = 0; piece < 2; ++piece) {
      const int qt = piece ? (31 - y) : y;
      const int qrow0 = qt * 64;
      const int nc = qt + 1;            // 64-key chunks for this q-tile
      const int hs = (nc + 1) >> 1;
      const int c0 = piece ? hs : 0;
      const int c1 = piece ? nc : hs;
      bf16x8 Qf[16];
      {
        const bf16* qp = qb + (size_t)((qrow0 + w * 16 + lr) * 4 + b) * 1024 + h * 512 + q * 8;
#pragma unroll
        for (int kk = 0; kk < 16; kk++) Qf[kk] = *(const bf16x8*)(qp + kk * 32);
      }
      // stage K[c0] (harmless in-range over-stage when c0==c1)
#pragma unroll
      for (int j = 0; j < 16; j++)
        gload16(krow0 + (size_t)((c0 * 64 + w * 16 + j) * 4) * 1024,
                &Ks[c0 & 1][(w * 16 + j) * 520]);
      __syncthreads();  // [B0] K[c0] visible
      const int myrow = qrow0 + w * 16 + q * 4;
      for (int t = c0; t <= c1; t++) {
        if (t < c1) {
          const int p = t & 1;
          const int kc = t * 64;
          // prefetch K[t+1] first — drained by this iter's end barrier
          if (t + 1 < c1) {
            const int kc2 = (t + 1) * 64;
#pragma unroll
            for (int j = 0; j < 16; j++)
              gload16(krow0 + (size_t)((kc2 + w * 16 + j) * 4) * 1024,
                      &Ks[1 - p][(w * 16 + j) * 520]);
          }
          f32x4 S0 = {}, S1 = {}, S2 = {}, S3 = {};
#pragma unroll
          for (int kk = 0; kk < 16; kk++) {
            const bf16x8 k0 = *(const bf16x8*)&Ks[p][lr * 520 + kk * 32 + q * 8];
            const bf16x8 k1 = *(const bf16x8*)&Ks[p][(16 + lr) * 520 + kk * 32 + q * 8];
            const bf16x8 k2 = *(const bf16x8*)&Ks[p][(32 + lr) * 520 + kk * 32 + q * 8];
            const bf16x8 k3 = *(const bf16x8*)&Ks[p][(48 + lr) * 520 + kk * 32 + q * 8];
            S0 = MFMA16x16x32(Qf[kk], k0, S0);
            S1 = MFMA16x16x32(Qf[kk], k1, S1);
            S2 = MFMA16x16x32(Qf[kk], k2, S2);
            S3 = MFMA16x16x32(Qf[kk], k3, S3);
          }
#pragma unroll
          for (int r = 0; r < 4; r++) {
            const int row = myrow + r;
            const float p0 = (kc + lr > row) ? 0.f : __expf(S0[r] * sc);
            const float p1 = (kc + 16 + lr > row) ? 0.f : __expf(S1[r] * sc);
            const float p2 = (kc + 32 + lr > row) ? 0.f : __expf(S2[r] * sc);
            const float p3 = (kc + 48 + lr > row) ? 0.f : __expf(S3[r] * sc);
            bf16* pr = &Ps[p][w][(q * 4 + r) * 72];
            pr[lr] = (bf16)p0;
            pr[16 + lr] = (bf16)p1;
            pr[32 + lr] = (bf16)p2;
            pr[48 + lr] = (bf16)p3;
          }
        }
        __syncthreads();  // [Bt] P[t] visible; K[t+1] landed; P[t-1] reads done
      }
    }
  } else {
    // ================= PV-waves =================
    const int pw = w - 4;  // 0..7, dims [64*pw, 64*pw+64)
    bf16x8 ones;
#pragma unroll
    for (int e = 0; e < 8; e++) ones[e] = (bf16)1.0f;
    const bf16* vbase = vtg + ((size_t)bh << 20) + (size_t)(pw * 64 + lr) * 2048 + q * 8;
    for (int piece = 0; piece < 2; ++piece) {
      const int qt = piece ? (31 - y) : y;
      const int qrow0 = qt * 64;
      const int nc = qt + 1;
      const int hs = (nc + 1) >> 1;
      const int c0 = piece ? hs : 0;
      const int c1 = piece ? nc : hs;
      f32x4 O[4][4] = {};
      f32x4 lac = {};
      __syncthreads();  // [B0]
      for (int t = c0; t <= c1; t++) {
        if (t > c0) {
          const int p = (t - 1) & 1;
          const int kc = (t - 1) * 64;
#pragma unroll
          for (int s = 0; s < 2; s++) {
            bf16x8 pa[4];
#pragma unroll
            for (int rt = 0; rt < 4; rt++)
              pa[rt] = *(const bf16x8*)&Ps[p][rt][lr * 72 + s * 32 + q * 8];
            if (pw < 4) {
              const bf16x8 psel = pw == 0 ? pa[0] : (pw == 1 ? pa[1] : (pw == 2 ? pa[2] : pa[3]));
              lac = MFMA16x16x32(psel, ones, lac);
            }
#pragma unroll
            for (int ct = 0; ct < 4; ct++) {
              const bf16x8 vf = *(const bf16x8*)(vbase + (size_t)(ct * 16) * 2048 + kc + s * 32);
#pragma unroll
              for (int rt = 0; rt < 4; rt++)
                O[rt][ct] = MFMA16x16x32(pa[rt], vf, O[rt][ct]);
            }
          }
        }
        __syncthreads();  // [Bt]
      }
      // ---- write partials: opart[half][bh][row 2048][dim 512] (= d_out) ----
      bf16* op = opart + (size_t)piece * (8u << 20) + (size_t)bh * (1u << 20);
#pragma unroll
      for (int rt = 0; rt < 4; rt++)
#pragma unroll
        for (int ct = 0; ct < 4; ct++)
#pragma unroll
          for (int r = 0; r < 4; r++)
            op[(size_t)(qrow0 + rt * 16 + q * 4 + r) * 512 + pw * 64 + ct * 16 + lr] =
                (bf16)O[rt][ct][r];
      if (lr == 0 && pw < 4) {
#pragma unroll
        for (int r = 0; r < 4; r++)
          lpart[piece * 16384 + bh * 2048 + qrow0 + pw * 16 + q * 4 + r] = lac[r];
      }
    }
  }
}

// ---------------- combine: ctx = (O0+O1)/(l0+l1), bf16 token-major ---------
__global__ __launch_bounds__(256) void attn_combine(
    const bf16* __restrict__ opart, const float* __restrict__ lpart,
    bf16* __restrict__ ctx)
{
  const int gid = blockIdx.x * 256 + threadIdx.x;
  const int bh = gid >> 17;
  const int rem = gid & 131071;
  const int row = rem >> 6;
  const int dc = (rem & 63) * 8;
  const size_t o = (size_t)bh * (1u << 20) + (size_t)row * 512 + dc;
  const bf16x8 a = *(const bf16x8*)(opart + o);
  const bf16x8 c = *(const bf16x8*)(opart + (size_t)(8u << 20) + o);
  const float inv = 1.0f /
      (lpart[bh * 2048 + row] + lpart[16384 + bh * 2048 + row]);
  bf16x8 ov;
#pragma unroll
  for (int e = 0; e < 8; e++) ov[e] = (bf16)(((float)a[e] + (float)c[e]) * inv);
  const int b = bh >> 1, h = bh & 1;
  *(bf16x8*)(ctx + (size_t)(row * 4 + b) * 1024 + h * 512 + dc) = ov;
}

// ---------------------------------------------------------------------------
extern "C" void kernel_launch(void* const* d_in, const int* in_sizes, int n_in,
                              void* d_out, int out_size, void* d_ws, size_t ws_size,
                              hipStream_t stream)
{
  (void)in_sizes; (void)n_in; (void)out_size; (void)ws_size;
  const float* x    = (const float*)d_in[0];
  const float* wn1  = (const float*)d_in[1];
  const float* wqkv = (const float*)d_in[2];
  const float* bqkv = (const float*)d_in[3];
  const float* wout = (const float*)d_in[4];
  const float* bout = (const float*)d_in[5];
  const float* wn2  = (const float*)d_in[6];
  const float* W1   = (const float*)d_in[7];
  const float* b1   = (const float*)d_in[8];
  const float* W2   = (const float*)d_in[9];
  const float* b2   = (const float*)d_in[10];
  float* out = (float*)d_out;

  char* ws = (char*)d_ws;
  const size_t Mi = 1u << 20;
  bf16* S0v = (bf16*)(ws);              // h -> vt -> m
  bf16* S1v = (bf16*)(ws + 16 * Mi);    // q -> ctx
  bf16* S2v = (bf16*)(ws + 32 * Mi);    // k -> g (lower half)
  bf16* S3v = (bf16*)(ws + 48 * Mi);    // vtmp -> l -> g (upper half)
  bf16* wqb = (bf16*)(ws + 64 * Mi);
  bf16* wob = (bf16*)(ws + 70 * Mi);
  bf16* w1b = (bf16*)(ws + 72 * Mi);
  bf16* w2b = (bf16*)(ws + 76 * Mi);
  const int M = 8192;

  wcvt4<<<8192, 256, 0, stream>>>(wqkv, wqb, wout, wob, W1, w1b, W2, w2b);
  rmsnorm_kernel<<<8192, 256, 0, stream>>>(x, wn1, S0v);
  gemm_bt2<EPI_QKV><<<64 * 24, 256, 0, stream>>>(
      S0v, wqb, bqkv, nullptr, nullptr, S1v, S2v, S3v, M, 3072, 1024);
  vtrans_kernel<<<dim3(32, 8, 8), 256, 0, stream>>>(S3v, S0v);
  attn_kernel<<<dim3(8, 32), 768, 0, stream>>>(
      S1v, S2v, S0v, (bf16*)d_out, (float*)S3v);
  attn_combine<<<4096, 256, 0, stream>>>((const bf16*)d_out, (const float*)S3v, S1v);
  gemm_bt2<EPI_RES><<<64 * 8, 256, 0, stream>>>(
      S1v, wob, bout, x, out, nullptr, nullptr, nullptr, M, 1024, 1024);
  rmsnorm_kernel<<<8192, 256, 0, stream>>>(out, wn2, S0v);
  gemm256p<<<256, 512, 0, stream>>>(S0v, w1b, b1, S2v, M, 2048, 1024);
  gemm_bt2<EPI_RES><<<64 * 8, 256, 0, stream>>>(
      S2v, w2b, b2, out, out, nullptr, nullptr, nullptr, M, 1024, 2048);
}

// Round 12
// 416.806 us; speedup vs baseline: 1.0260x; 1.0260x over previous
//
#include <hip/hip_runtime.h>

// ---------------------------------------------------------------------------
// TransformerBlock on MI355X (gfx950) — round 16.
// Token-major: t = s*B + b, x is (8192, 1024).
// r15's gemm256p REVERTED (78.5us, 3.1M conflicts, 16.6% MfmaUtil — third
// failed 256^2 deep-pipeline port; branch abandoned). MLP1 back on gemm_bt2.
// NEW: prep_kernel fuses wcvt4 + rmsnorm1 (independent inputs; one launch
// boundary saved). GEMM = T3 2-phase 128^2 (256,4). Attention v9 (64-key
// chunks, 12 waves) unchanged. Attn LDS conflict count re-derived as the
// 1KB-per-b128 phase floor (uniform 8 lanes/slot) — not a fixable pattern.
// ws slots (MiB): S0[0,16) h/vt/m; S1[16,32) q/ctx; S2[32,48) k/g.lo;
// S3[48,64) vtmp/l/g.hi; [64,80) bf16 weights. d_out = attn partial scratch.
// ---------------------------------------------------------------------------

typedef __bf16 bf16;
typedef bf16 bf16x8 __attribute__((ext_vector_type(8)));
typedef bf16 bf16x4 __attribute__((ext_vector_type(4)));
typedef float f32x4 __attribute__((ext_vector_type(4)));

#define MFMA16x16x32(A, B, C) __builtin_amdgcn_mfma_f32_16x16x32_bf16(A, B, C, 0, 0, 0)

__device__ __forceinline__ void gload16(const void* g, void* l) {
  __builtin_amdgcn_global_load_lds(
      (const __attribute__((address_space(1))) void*)g,
      (__attribute__((address_space(3))) void*)l, 16, 0, 0);
}

// ---------------- prep: rmsnorm1 (blocks 0..8191) + wcvt x4 (8192..16383) ---
__global__ __launch_bounds__(256) void prep_kernel(
    const float* __restrict__ x, const float* __restrict__ wn1,
    bf16* __restrict__ hout,
    const float* __restrict__ s0, bf16* __restrict__ d0,
    const float* __restrict__ s1, bf16* __restrict__ d1,
    const float* __restrict__ s2, bf16* __restrict__ d2,
    const float* __restrict__ s3, bf16* __restrict__ d3)
{
  const int tid = threadIdx.x;
  if (blockIdx.x < 8192) {
    const int row = blockIdx.x;
    const float4 v = *(const float4*)(x + (size_t)row * 1024 + tid * 4);
    float ss = v.x * v.x + v.y * v.y + v.z * v.z + v.w * v.w;
#pragma unroll
    for (int off = 1; off < 64; off <<= 1) ss += __shfl_xor(ss, off, 64);
    __shared__ float red[4];
    if ((tid & 63) == 0) red[tid >> 6] = ss;
    __syncthreads();
    const float tot = red[0] + red[1] + red[2] + red[3];
    const float inv = rsqrtf(tot * (1.0f / 1024.0f) + 1e-8f);
    const float4 g = *(const float4*)(wn1 + tid * 4);
    bf16x4 o;
    o[0] = (bf16)(v.x * g.x * inv);
    o[1] = (bf16)(v.y * g.y * inv);
    o[2] = (bf16)(v.z * g.z * inv);
    o[3] = (bf16)(v.w * g.w * inv);
    *(bf16x4*)(hout + (size_t)row * 1024 + tid * 4) = o;
  } else {
    const int gid = (blockIdx.x - 8192) * 256 + tid;  // quad index, 2097152
    const float* s; bf16* d; int off;
    if (gid < 786432)       { s = s0; d = d0; off = gid; }
    else if (gid < 1048576) { s = s1; d = d1; off = gid - 786432; }
    else if (gid < 1572864) { s = s2; d = d2; off = gid - 1048576; }
    else                    { s = s3; d = d3; off = gid - 1572864; }
    const int i = off * 4;
    const float4 v = *(const float4*)(s + i);
    bf16x4 o;
    o[0] = (bf16)v.x; o[1] = (bf16)v.y; o[2] = (bf16)v.z; o[3] = (bf16)v.w;
    *(bf16x4*)(d + i) = o;
  }
}

// ---------------- RMSNorm: (8192 x 1024) f32 -> bf16 -----------------------
__global__ __launch_bounds__(256) void rmsnorm_kernel(
    const float* __restrict__ x, const float* __restrict__ w, bf16* __restrict__ out)
{
  const int row = blockIdx.x;
  const int tid = threadIdx.x;
  const float4 v = *(const float4*)(x + (size_t)row * 1024 + tid * 4);
  float ss = v.x * v.x + v.y * v.y + v.z * v.z + v.w * v.w;
#pragma unroll
  for (int off = 1; off < 64; off <<= 1) ss += __shfl_xor(ss, off, 64);
  __shared__ float red[4];
  if ((tid & 63) == 0) red[tid >> 6] = ss;
  __syncthreads();
  const float tot = red[0] + red[1] + red[2] + red[3];
  const float inv = rsqrtf(tot * (1.0f / 1024.0f) + 1e-8f);
  const float4 g = *(const float4*)(w + tid * 4);
  bf16x4 o;
  o[0] = (bf16)(v.x * g.x * inv);
  o[1] = (bf16)(v.y * g.y * inv);
  o[2] = (bf16)(v.z * g.z * inv);
  o[3] = (bf16)(v.w * g.w * inv);
  *(bf16x4*)(out + (size_t)row * 1024 + tid * 4) = o;
}

// ---------------- GEMM: C = A * W^T + bias, 128x128, 2-phase ---------------
enum { EPI_BF16 = 0, EPI_RES = 1, EPI_GELU = 2, EPI_QKV = 3 };

template <int EPI>
__global__ __launch_bounds__(256, 4) void gemm_bt2(
    const bf16* __restrict__ A,   // M x K
    const bf16* __restrict__ B,   // N x K
    const float* __restrict__ bias,
    const float* res,             // may alias outF
    float* outF, bf16* outQ, bf16* outK, bf16* outV,
    int M, int N, int K)
{
  __shared__ bf16 lds[2][8192];  // 2 buffers x (As 4096 + Bs 4096) = 32 KB
  const int tid = threadIdx.x;
  // super-rows of 16 bm: concurrent blocks share a 4 MB A-slice (L2-resident)
  const int Nb = N >> 7;
  const int lin = blockIdx.x;
  const int sup = lin / (Nb << 4);
  const int rem = lin - sup * (Nb << 4);
  const int bm = (sup << 4) + (rem & 15);
  const int bn = rem >> 4;
  const int w = tid >> 6, lane = tid & 63;
  const int q = lane >> 4, lr = lane & 15;
  const int wr = (w >> 1) * 64, wc = (w & 1) * 64;
  f32x4 acc[4][4] = {};
  const int srow = lane >> 2;
  const int gch = ((lane & 3) - ((lane >> 3) & 3)) & 3;
  const bf16* Ab = A + (size_t)(bm * 128) * K;
  const bf16* Bb = B + (size_t)(bn * 128) * K;
  const int sw = ((q + (lr >> 1)) & 3) * 16;
  const int NK = K >> 5;

#define STAGE(dst, k0)                                                        \
  {                                                                           \
    bf16* De = (dst);                                                         \
    _Pragma("unroll")                                                         \
    for (int c = 0; c < 2; c++) {                                             \
      const int r = (w * 2 + c) * 16 + srow;                                  \
      gload16(Ab + (size_t)r * K + (k0) + gch * 8, De + (w * 2 + c) * 512);   \
      gload16(Bb + (size_t)r * K + (k0) + gch * 8, De + 4096 + (w * 2 + c) * 512); \
    }                                                                         \
  }

  STAGE(&lds[0][0], 0);
  __syncthreads();  // tile 0 visible
#pragma unroll 1
  for (int u = 0; u < NK; ++u) {
    bf16* cur = &lds[u & 1][0];
    bf16* nxt = &lds[(u + 1) & 1][0];
    // T3 minimum 2-phase: issue next-tile stage FIRST, compute under it.
    if (u + 1 < NK) STAGE(nxt, (u + 1) * 32);
    const char* As = (const char*)cur;
    const char* Bs = (const char*)(cur + 4096);
    bf16x8 af[4], bfr[4];
#pragma unroll
    for (int mt = 0; mt < 4; mt++)
      af[mt] = *(const bf16x8*)(As + (wr + mt * 16 + lr) * 64 + sw);
#pragma unroll
    for (int nt = 0; nt < 4; nt++)
      bfr[nt] = *(const bf16x8*)(Bs + (wc + nt * 16 + lr) * 64 + sw);
#pragma unroll
    for (int mt = 0; mt < 4; mt++)
#pragma unroll
      for (int nt = 0; nt < 4; nt++)
        acc[mt][nt] = MFMA16x16x32(af[mt], bfr[nt], acc[mt][nt]);
    __syncthreads();
  }
#undef STAGE

  const int gm0 = bm * 128 + wr + q * 4;
  const int gn0 = bn * 128 + wc + lr;
  bf16* outs = nullptr;
  if constexpr (EPI == EPI_QKV) {
    const int reg = (bn * 128) >> 10;
    outs = reg == 0 ? outQ : (reg == 1 ? outK : outV);
  } else {
    outs = outQ;
  }
#pragma unroll
  for (int nt = 0; nt < 4; nt++) {
    const int gn = gn0 + nt * 16;
    const float bv = bias[gn];
#pragma unroll
    for (int mt = 0; mt < 4; mt++) {
#pragma unroll
      for (int r = 0; r < 4; r++) {
        float v = acc[mt][nt][r] + bv;
        const int gm = gm0 + mt * 16 + r;
        if constexpr (EPI == EPI_GELU) {
          v = 0.5f * v * (1.0f + erff(v * 0.70710678118654752f));
          outs[(size_t)gm * N + gn] = (bf16)v;
        } else if constexpr (EPI == EPI_BF16) {
          outs[(size_t)gm * N + gn] = (bf16)v;
        } else if constexpr (EPI == EPI_QKV) {
          outs[(size_t)gm * 1024 + (gn & 1023)] = (bf16)v;
        } else {
          const size_t idx = (size_t)gm * N + gn;
          outF[idx] = v + res[idx];
        }
      }
    }
  }
}

// ---------------- V transpose: vtmp (t,n) -> vt[bh][dim][key] --------------
__global__ __launch_bounds__(256) void vtrans_kernel(
    const bf16* __restrict__ vtmp, bf16* __restrict__ vt)
{
  __shared__ bf16 tile[64 * 72];
  const int kt = blockIdx.x;
  const int dt = blockIdx.y;
  const int bh = blockIdx.z;
  const int b = bh >> 1, h = bh & 1;
  const int tid = threadIdx.x;
#pragma unroll
  for (int it = 0; it < 2; it++) {
    const int key = it * 32 + (tid >> 3);
    const int dc = (tid & 7) * 8;
    const bf16x8 v = *(const bf16x8*)(vtmp +
        (size_t)((kt * 64 + key) * 4 + b) * 1024 + h * 512 + dt * 64 + dc);
    *(bf16x8*)&tile[key * 72 + dc] = v;
  }
  __syncthreads();
#pragma unroll
  for (int it = 0; it < 2; it++) {
    const int dim = it * 32 + (tid >> 3);
    const int kc = (tid & 7) * 8;
    bf16x8 o;
#pragma unroll
    for (int j = 0; j < 8; j++) o[j] = tile[(kc + j) * 72 + dim];
    *(bf16x8*)(vt + (size_t)bh * (1u << 20) +
               (size_t)(dt * 64 + dim) * 2048 + kt * 64 + kc) = o;
  }
}

// ---------------- Attention v9: 12 waves, 64-key chunks --------------------
__global__ __launch_bounds__(768, 3) void attn_kernel(
    const bf16* __restrict__ qb, const bf16* __restrict__ kb,
    const bf16* __restrict__ vtg, bf16* __restrict__ opart,
    float* __restrict__ lpart)
{
  __shared__ bf16 Ks[2][64 * 520];   // 2 x 66560 B
  __shared__ bf16 Ps[2][4][16 * 72]; // 2 x  9216 B  (151552 total)
  const int bh = blockIdx.x;          // 0..7 -> XCD affinity
  const int y = blockIdx.y;           // 0..31
  const int b = bh >> 1, h = bh & 1;
  const int tid = threadIdx.x;
  const int w = tid >> 6, lane = tid & 63;
  const int q = lane >> 4, lr = lane & 15;
  const float sc = 0.044194173824159216f;  // 1/sqrt(512)

  if (w < 4) {
    // ================= S-waves =================
    const bf16* krow0 = kb + (size_t)b * 1024 + h * 512 + lane * 8;  // per-lane 16B
    for (int piece = 0; piece < 2; ++piece) {
      const int qt = piece ? (31 - y) : y;
      const int qrow0 = qt * 64;
      const int nc = qt + 1;            // 64-key chunks for this q-tile
      const int hs = (nc + 1) >> 1;
      const int c0 = piece ? hs : 0;
      const int c1 = piece ? nc : hs;
      bf16x8 Qf[16];
      {
        const bf16* qp = qb + (size_t)((qrow0 + w * 16 + lr) * 4 + b) * 1024 + h * 512 + q * 8;
#pragma unroll
        for (int kk = 0; kk < 16; kk++) Qf[kk] = *(const bf16x8*)(qp + kk * 32);
      }
      // stage K[c0] (harmless in-range over-stage when c0==c1)
#pragma unroll
      for (int j = 0; j < 16; j++)
        gload16(krow0 + (size_t)((c0 * 64 + w * 16 + j) * 4) * 1024,
                &Ks[c0 & 1][(w * 16 + j) * 520]);
      __syncthreads();  // [B0] K[c0] visible
      const int myrow = qrow0 + w * 16 + q * 4;
      for (int t = c0; t <= c1; t++) {
        if (t < c1) {
          const int p = t & 1;
          const int kc = t * 64;
          // prefetch K[t+1] first — drained by this iter's end barrier
          if (t + 1 < c1) {
            const int kc2 = (t + 1) * 64;
#pragma unroll
            for (int j = 0; j < 16; j++)
              gload16(krow0 + (size_t)((kc2 + w * 16 + j) * 4) * 1024,
                      &Ks[1 - p][(w * 16 + j) * 520]);
          }
          f32x4 S0 = {}, S1 = {}, S2 = {}, S3 = {};
#pragma unroll
          for (int kk = 0; kk < 16; kk++) {
            const bf16x8 k0 = *(const bf16x8*)&Ks[p][lr * 520 + kk * 32 + q * 8];
            const bf16x8 k1 = *(const bf16x8*)&Ks[p][(16 + lr) * 520 + kk * 32 + q * 8];
            const bf16x8 k2 = *(const bf16x8*)&Ks[p][(32 + lr) * 520 + kk * 32 + q * 8];
            const bf16x8 k3 = *(const bf16x8*)&Ks[p][(48 + lr) * 520 + kk * 32 + q * 8];
            S0 = MFMA16x16x32(Qf[kk], k0, S0);
            S1 = MFMA16x16x32(Qf[kk], k1, S1);
            S2 = MFMA16x16x32(Qf[kk], k2, S2);
            S3 = MFMA16x16x32(Qf[kk], k3, S3);
          }
#pragma unroll
          for (int r = 0; r < 4; r++) {
            const int row = myrow + r;
            const float p0 = (kc + lr > row) ? 0.f : __expf(S0[r] * sc);
            const float p1 = (kc + 16 + lr > row) ? 0.f : __expf(S1[r] * sc);
            const float p2 = (kc + 32 + lr > row) ? 0.f : __expf(S2[r] * sc);
            const float p3 = (kc + 48 + lr > row) ? 0.f : __expf(S3[r] * sc);
            bf16* pr = &Ps[p][w][(q * 4 + r) * 72];
            pr[lr] = (bf16)p0;
            pr[16 + lr] = (bf16)p1;
            pr[32 + lr] = (bf16)p2;
            pr[48 + lr] = (bf16)p3;
          }
        }
        __syncthreads();  // [Bt] P[t] visible; K[t+1] landed; P[t-1] reads done
      }
    }
  } else {
    // ================= PV-waves =================
    const int pw = w - 4;  // 0..7, dims [64*pw, 64*pw+64)
    bf16x8 ones;
#pragma unroll
    for (int e = 0; e < 8; e++) ones[e] = (bf16)1.0f;
    const bf16* vbase = vtg + ((size_t)bh << 20) + (size_t)(pw * 64 + lr) * 2048 + q * 8;
    for (int piece = 0; piece < 2; ++piece) {
      const int qt = piece ? (31 - y) : y;
      const int qrow0 = qt * 64;
      const int nc = qt + 1;
      const int hs = (nc + 1) >> 1;
      const int c0 = piece ? hs : 0;
      const int c1 = piece ? nc : hs;
      f32x4 O[4][4] = {};
      f32x4 lac = {};
      __syncthreads();  // [B0]
      for (int t = c0; t <= c1; t++) {
        if (t > c0) {
          const int p = (t - 1) & 1;
          const int kc = (t - 1) * 64;
#pragma unroll
          for (int s = 0; s < 2; s++) {
            bf16x8 pa[4];
#pragma unroll
            for (int rt = 0; rt < 4; rt++)
              pa[rt] = *(const bf16x8*)&Ps[p][rt][lr * 72 + s * 32 + q * 8];
            if (pw < 4) {
              const bf16x8 psel = pw == 0 ? pa[0] : (pw == 1 ? pa[1] : (pw == 2 ? pa[2] : pa[3]));
              lac = MFMA16x16x32(psel, ones, lac);
            }
#pragma unroll
            for (int ct = 0; ct < 4; ct++) {
              const bf16x8 vf = *(const bf16x8*)(vbase + (size_t)(ct * 16) * 2048 + kc + s * 32);
#pragma unroll
              for (int rt = 0; rt < 4; rt++)
                O[rt][ct] = MFMA16x16x32(pa[rt], vf, O[rt][ct]);
            }
          }
        }
        __syncthreads();  // [Bt]
      }
      // ---- write partials: opart[half][bh][row 2048][dim 512] (= d_out) ----
      bf16* op = opart + (size_t)piece * (8u << 20) + (size_t)bh * (1u << 20);
#pragma unroll
      for (int rt = 0; rt < 4; rt++)
#pragma unroll
        for (int ct = 0; ct < 4; ct++)
#pragma unroll
          for (int r = 0; r < 4; r++)
            op[(size_t)(qrow0 + rt * 16 + q * 4 + r) * 512 + pw * 64 + ct * 16 + lr] =
                (bf16)O[rt][ct][r];
      if (lr == 0 && pw < 4) {
#pragma unroll
        for (int r = 0; r < 4; r++)
          lpart[piece * 16384 + bh * 2048 + qrow0 + pw * 16 + q * 4 + r] = lac[r];
      }
    }
  }
}

// ---------------- combine: ctx = (O0+O1)/(l0+l1), bf16 token-major ---------
__global__ __launch_bounds__(256) void attn_combine(
    const bf16* __restrict__ opart, const float* __restrict__ lpart,
    bf16* __restrict__ ctx)
{
  const int gid = blockIdx.x * 256 + threadIdx.x;
  const int bh = gid >> 17;
  const int rem = gid & 131071;
  const int row = rem >> 6;
  const int dc = (rem & 63) * 8;
  const size_t o = (size_t)bh * (1u << 20) + (size_t)row * 512 + dc;
  const bf16x8 a = *(const bf16x8*)(opart + o);
  const bf16x8 c = *(const bf16x8*)(opart + (size_t)(8u << 20) + o);
  const float inv = 1.0f /
      (lpart[bh * 2048 + row] + lpart[16384 + bh * 2048 + row]);
  bf16x8 ov;
#pragma unroll
  for (int e = 0; e < 8; e++) ov[e] = (bf16)(((float)a[e] + (float)c[e]) * inv);
  const int b = bh >> 1, h = bh & 1;
  *(bf16x8*)(ctx + (size_t)(row * 4 + b) * 1024 + h * 512 + dc) = ov;
}

// ---------------------------------------------------------------------------
extern "C" void kernel_launch(void* const* d_in, const int* in_sizes, int n_in,
                              void* d_out, int out_size, void* d_ws, size_t ws_size,
                              hipStream_t stream)
{
  (void)in_sizes; (void)n_in; (void)out_size; (void)ws_size;
  const float* x    = (const float*)d_in[0];
  const float* wn1  = (const float*)d_in[1];
  const float* wqkv = (const float*)d_in[2];
  const float* bqkv = (const float*)d_in[3];
  const float* wout = (const float*)d_in[4];
  const float* bout = (const float*)d_in[5];
  const float* wn2  = (const float*)d_in[6];
  const float* W1   = (const float*)d_in[7];
  const float* b1   = (const float*)d_in[8];
  const float* W2   = (const float*)d_in[9];
  const float* b2   = (const float*)d_in[10];
  float* out = (float*)d_out;

  char* ws = (char*)d_ws;
  const size_t Mi = 1u << 20;
  bf16* S0v = (bf16*)(ws);              // h -> vt -> m
  bf16* S1v = (bf16*)(ws + 16 * Mi);    // q -> ctx
  bf16* S2v = (bf16*)(ws + 32 * Mi);    // k -> g (lower half)
  bf16* S3v = (bf16*)(ws + 48 * Mi);    // vtmp -> l -> g (upper half)
  bf16* wqb = (bf16*)(ws + 64 * Mi);
  bf16* wob = (bf16*)(ws + 70 * Mi);
  bf16* w1b = (bf16*)(ws + 72 * Mi);
  bf16* w2b = (bf16*)(ws + 76 * Mi);
  const int M = 8192;

  prep_kernel<<<16384, 256, 0, stream>>>(
      x, wn1, S0v, wqkv, wqb, wout, wob, W1, w1b, W2, w2b);
  gemm_bt2<EPI_QKV><<<64 * 24, 256, 0, stream>>>(
      S0v, wqb, bqkv, nullptr, nullptr, S1v, S2v, S3v, M, 3072, 1024);
  vtrans_kernel<<<dim3(32, 8, 8), 256, 0, stream>>>(S3v, S0v);
  attn_kernel<<<dim3(8, 32), 768, 0, stream>>>(
      S1v, S2v, S0v, (bf16*)d_out, (float*)S3v);
  attn_combine<<<4096, 256, 0, stream>>>((const bf16*)d_out, (const float*)S3v, S1v);
  gemm_bt2<EPI_RES><<<64 * 8, 256, 0, stream>>>(
      S1v, wob, bout, x, out, nullptr, nullptr, nullptr, M, 1024, 1024);
  rmsnorm_kernel<<<8192, 256, 0, stream>>>(out, wn2, S0v);
  gemm_bt2<EPI_GELU><<<64 * 16, 256, 0, stream>>>(
      S0v, w1b, b1, nullptr, nullptr, S2v, nullptr, nullptr, M, 2048, 1024);
  gemm_bt2<EPI_RES><<<64 * 8, 256, 0, stream>>>(
      S2v, w2b, b2, out, out, nullptr, nullptr, nullptr, M, 1024, 2048);
}